// Round 1
// baseline (49915.405 us; speedup 1.0000x reference)
//
#include <hip/hip_runtime.h>
#include <hip/hip_bf16.h>
#include <math.h>

// Problem dims (fixed)
#define NOTES 78
#define IN_DIM 80
#define T_HID 64
#define N_HID 2
#define BATCH 64
#define TLEN 128
#define NSEQ (BATCH * NOTES)          // 4992 time-LSTM sequences
#define NBT  (BATCH * TLEN)           // 8192 note-LSTM sequences
#define SB   8                        // sequences per block in time-LSTM

__device__ __forceinline__ float dot4(float4 a, float4 b) {
    return a.x * b.x + a.y * b.y + a.z * b.z + a.w * b.w;
}
__device__ __forceinline__ float sigf(float x) {
    return 1.0f / (1.0f + expf(-x));
}

// ---------------------------------------------------------------------------
// Kernel A: fused time-LSTM. x:(4992,128,80). Weights w_ih:(256,80) w_hh:(256,64).
// Each thread owns gate row g = threadIdx.x, weights in registers.
// Block handles SB=8 sequences; h/c from zero state; writes tout[t][s][u] (t-major).
// ---------------------------------------------------------------------------
__global__ __launch_bounds__(256, 2)
void time_lstm_kernel(const float* __restrict__ x,
                      const float* __restrict__ w_ih,
                      const float* __restrict__ w_hh,
                      const float* __restrict__ b_ih,
                      const float* __restrict__ b_hh,
                      float* __restrict__ tout) {
    __shared__ float xbuf[SB][IN_DIM];   // 8*80*4   = 2.5 KB
    __shared__ float hbuf[SB][T_HID];    // 8*64*4   = 2   KB
    __shared__ float G[SB][4 * T_HID];   // 8*256*4  = 8   KB

    const int tid = threadIdx.x;
    const int g = tid;                   // gate row 0..255
    const int s0 = blockIdx.x * SB;      // first global sequence of this block

    // --- load this thread's weight rows into registers (one-time) ---
    float4 wih[IN_DIM / 4];
    float4 whh[T_HID / 4];
    const float4* wih_p = (const float4*)(w_ih + (size_t)g * IN_DIM);
    const float4* whh_p = (const float4*)(w_hh + (size_t)g * T_HID);
#pragma unroll
    for (int j = 0; j < IN_DIM / 4; j++) wih[j] = wih_p[j];
#pragma unroll
    for (int j = 0; j < T_HID / 4; j++) whh[j] = whh_p[j];
    const float bias = b_ih[g] + b_hh[g];
    const int gtype = g >> 6;            // 0=i 1=f 2=g(tanh) 3=o  (wave-uniform)

    // zero h, load x for t=0
    for (int i = tid; i < SB * T_HID; i += 256) ((float*)hbuf)[i] = 0.0f;
    const int pls = tid / (IN_DIM / 4);  // prefetch: seq within block
    const int pj  = tid % (IN_DIM / 4);  // prefetch: float4 index
    if (tid < SB * (IN_DIM / 4)) {
        ((float4*)xbuf[pls])[pj] =
            ((const float4*)(x + ((size_t)(s0 + pls) * TLEN) * IN_DIM))[pj];
    }

    // cell state: thread (uu, sgrp) owns units (uu, s=sgrp) and (uu, s=sgrp+4)
    const int uu = tid & 63;
    const int sgrp = tid >> 6;
    float c0 = 0.0f, c1 = 0.0f;

    __syncthreads();

    for (int t = 0; t < TLEN; t++) {
        // ---- phase A: gate pre-activations for SB sequences ----
        float acc[SB];
#pragma unroll
        for (int s = 0; s < SB; s++) acc[s] = bias;
#pragma unroll
        for (int j = 0; j < IN_DIM / 4; j++) {
            const float4 w = wih[j];
#pragma unroll
            for (int s = 0; s < SB; s++) {
                acc[s] += dot4(w, ((const float4*)xbuf[s])[j]);
            }
        }
#pragma unroll
        for (int j = 0; j < T_HID / 4; j++) {
            const float4 w = whh[j];
#pragma unroll
            for (int s = 0; s < SB; s++) {
                acc[s] += dot4(w, ((const float4*)hbuf[s])[j]);
            }
        }

        // prefetch x(t+1) into registers (completed before LDS write in phase B)
        float4 xp;
        const bool pf = (t + 1 < TLEN) && (tid < SB * (IN_DIM / 4));
        if (pf) {
            xp = ((const float4*)(x + ((size_t)(s0 + pls) * TLEN + (t + 1)) * IN_DIM))[pj];
        }

        // activation (wave-uniform branch) + stage gates
#pragma unroll
        for (int s = 0; s < SB; s++) {
            float v = acc[s];
            v = (gtype == 2) ? tanhf(v) : sigf(v);
            G[s][g] = v;
        }
        __syncthreads();

        // ---- phase B: LSTM state update (2 (unit,seq) pairs per thread) ----
        {
            const int s = sgrp;
            const float iv = G[s][uu], fv = G[s][64 + uu];
            const float gv = G[s][128 + uu], ov = G[s][192 + uu];
            c0 = fv * c0 + iv * gv;
            const float h = ov * tanhf(c0);
            hbuf[s][uu] = h;
            tout[((size_t)t * NSEQ + (s0 + s)) * T_HID + uu] = h;
        }
        {
            const int s = sgrp + 4;
            const float iv = G[s][uu], fv = G[s][64 + uu];
            const float gv = G[s][128 + uu], ov = G[s][192 + uu];
            c1 = fv * c1 + iv * gv;
            const float h = ov * tanhf(c1);
            hbuf[s][uu] = h;
            tout[((size_t)t * NSEQ + (s0 + s)) * T_HID + uu] = h;
        }
        if (pf) ((float4*)xbuf[pls])[pj] = xp;
        __syncthreads();
    }
}

// ---------------------------------------------------------------------------
// Kernel B: gxn = time_out @ w_ih_n.T + b_ih_n + b_hh_n
// tout is [t][s][64] (row r = t*4992 + s); output gxn is [note][bt][8]
// with bt = b*128 + t, so the scan kernel reads coalesced per note step.
// ---------------------------------------------------------------------------
__global__ __launch_bounds__(256)
void note_gx_kernel(const float* __restrict__ tout,
                    const float* __restrict__ w_ih_n,
                    const float* __restrict__ b_ih_n,
                    const float* __restrict__ b_hh_n,
                    float* __restrict__ gxn) {
    __shared__ float w[4 * N_HID][T_HID];   // 8*64*4 = 2 KB
    __shared__ float bb[4 * N_HID];
    const int tid = threadIdx.x;
    for (int i = tid; i < 4 * N_HID * T_HID; i += 256) ((float*)w)[i] = w_ih_n[i];
    if (tid < 4 * N_HID) bb[tid] = b_ih_n[tid] + b_hh_n[tid];
    __syncthreads();

    const size_t r = (size_t)blockIdx.x * 256 + tid;      // < 638976
    const float4* row = (const float4*)(tout + r * T_HID);

    float acc[8];
#pragma unroll
    for (int j = 0; j < 8; j++) acc[j] = bb[j];
#pragma unroll
    for (int k4 = 0; k4 < T_HID / 4; k4++) {
        const float4 xv = row[k4];
#pragma unroll
        for (int j = 0; j < 8; j++) {
            acc[j] += dot4(((const float4*)w[j])[k4], xv);
        }
    }
    const int t = (int)(r / NSEQ);
    const int s = (int)(r % NSEQ);
    const int b = s / NOTES, n = s % NOTES;
    const int bt = b * TLEN + t;
    float* o = gxn + ((size_t)n * NBT + bt) * 8;
    float4 o0 = make_float4(acc[0], acc[1], acc[2], acc[3]);
    float4 o1 = make_float4(acc[4], acc[5], acc[6], acc[7]);
    ((float4*)o)[0] = o0;
    ((float4*)o)[1] = o1;
}

// ---------------------------------------------------------------------------
// Kernel C: note-LSTM scan over 78 notes, fresh zero state per (b,t).
// One thread per bt = b*128+t. Threshold > 0.5 -> {1,0}.
// ---------------------------------------------------------------------------
__global__ __launch_bounds__(256)
void note_scan_kernel(const float* __restrict__ gxn,
                      const float* __restrict__ w_hh_n,
                      float* __restrict__ out) {
    const int bt = blockIdx.x * 256 + threadIdx.x;        // < 8192
    float wh[16];
#pragma unroll
    for (int i = 0; i < 16; i++) wh[i] = w_hh_n[i];       // [8][2] row-major
    float h0 = 0.f, h1 = 0.f, c0 = 0.f, c1 = 0.f;
    for (int n = 0; n < NOTES; n++) {
        const float4* gp = (const float4*)(gxn + ((size_t)n * NBT + bt) * 8);
        const float4 ga = gp[0], gb = gp[1];
        const float i0 = ga.x + wh[0] * h0 + wh[1] * h1;
        const float i1 = ga.y + wh[2] * h0 + wh[3] * h1;
        const float f0 = ga.z + wh[4] * h0 + wh[5] * h1;
        const float f1 = ga.w + wh[6] * h0 + wh[7] * h1;
        const float g0 = gb.x + wh[8] * h0 + wh[9] * h1;
        const float g1 = gb.y + wh[10] * h0 + wh[11] * h1;
        const float o0 = gb.z + wh[12] * h0 + wh[13] * h1;
        const float o1 = gb.w + wh[14] * h0 + wh[15] * h1;
        c0 = sigf(f0) * c0 + sigf(i0) * tanhf(g0);
        c1 = sigf(f1) * c1 + sigf(i1) * tanhf(g1);
        h0 = sigf(o0) * tanhf(c0);
        h1 = sigf(o1) * tanhf(c1);
        out[(size_t)bt * (NOTES * N_HID) + n * 2 + 0] = (h0 > 0.5f) ? 1.0f : 0.0f;
        out[(size_t)bt * (NOTES * N_HID) + n * 2 + 1] = (h1 > 0.5f) ? 1.0f : 0.0f;
    }
}

// ---------------------------------------------------------------------------
extern "C" void kernel_launch(void* const* d_in, const int* in_sizes, int n_in,
                              void* d_out, int out_size, void* d_ws, size_t ws_size,
                              hipStream_t stream) {
    const float* x      = (const float*)d_in[0];  // (64,78,128,80)
    const float* w_ih_t = (const float*)d_in[1];  // (256,80)
    const float* w_hh_t = (const float*)d_in[2];  // (256,64)
    const float* b_ih_t = (const float*)d_in[3];  // (256)
    const float* b_hh_t = (const float*)d_in[4];  // (256)
    const float* w_ih_n = (const float*)d_in[5];  // (8,64)
    const float* w_hh_n = (const float*)d_in[6];  // (8,2)
    const float* b_ih_n = (const float*)d_in[7];  // (8)
    const float* b_hh_n = (const float*)d_in[8];  // (8)
    float* out = (float*)d_out;                   // (64,128,156)

    // workspace layout: tout = [128][4992][64] fp32 (163.6 MB), then gxn = [78][8192][8] (20.4 MB)
    float* tout = (float*)d_ws;
    float* gxn  = tout + (size_t)TLEN * NSEQ * T_HID;

    time_lstm_kernel<<<NSEQ / SB, 256, 0, stream>>>(x, w_ih_t, w_hh_t, b_ih_t, b_hh_t, tout);
    note_gx_kernel<<<(TLEN * NSEQ) / 256, 256, 0, stream>>>(tout, w_ih_n, b_ih_n, b_hh_n, gxn);
    note_scan_kernel<<<NBT / 256, 256, 0, stream>>>(gxn, w_hh_n, out);
}

// Round 2
// 1432.587 us; speedup vs baseline: 34.8429x; 34.8429x over previous
//
#include <hip/hip_runtime.h>
#include <math.h>

// Problem dims (fixed)
#define NOTES 78
#define IN_DIM 80
#define T_HID 64
#define N_HID 2
#define BATCH 64
#define TLEN 128
#define NSEQ (BATCH * NOTES)          // 4992 time-LSTM sequences
#define NBT  (BATCH * TLEN)           // 8192 note-LSTM sequences
#define SB   8                        // sequences per block in time-LSTM

__device__ __forceinline__ float sigf(float x) {
    return 1.0f / (1.0f + expf(-x));
}

// ---------------------------------------------------------------------------
// Kernel A: fused time-LSTM + note-input projection.
//   512 threads/block, SB=8 sequences/block, 624 blocks.
//   Wave-uniform split-K: threads [0,256) hold w_ih row g in regs (80 VGPR),
//   threads [256,512) hold w_hh row g (64 VGPR, overlaid). Partial gate sums
//   staged in LDS (G0/G1); phase B combines, activates, updates c/h.
//   After each h update, all 512 threads compute gxn = h @ w_ih_n^T (+biases)
//   and write it directly in [note][bt][8] layout -- tout never materialized.
// ---------------------------------------------------------------------------
__global__ __launch_bounds__(512, 1)
void time_lstm_fused(const float* __restrict__ x,
                     const float* __restrict__ w_ih,
                     const float* __restrict__ w_hh,
                     const float* __restrict__ b_ih,
                     const float* __restrict__ b_hh,
                     const float* __restrict__ w_ih_n,
                     const float* __restrict__ b_ih_n,
                     const float* __restrict__ b_hh_n,
                     float* __restrict__ gxn) {
    __shared__ __align__(16) float xbuf[SB][IN_DIM];   // 2.5 KB
    __shared__ __align__(16) float hbuf[SB][T_HID];    // 2 KB
    __shared__ float G0[SB][256];                      // 8 KB  x-part + bias
    __shared__ float G1[SB][256];                      // 8 KB  h-part

    const int tid  = threadIdx.x;
    const int s0   = blockIdx.x * SB;
    const int g    = tid & 255;          // gate row
    const int half = tid >> 8;           // 0: x-part, 1: h-part (wave-uniform)

    // ---- weight rows in registers (overlaid union: max 20 float4 = 80 VGPR) ----
    float4 w[20];
    if (half == 0) {
        const float4* p = (const float4*)(w_ih + (size_t)g * IN_DIM);
#pragma unroll
        for (int j = 0; j < 20; j++) w[j] = p[j];
    } else {
        const float4* p = (const float4*)(w_hh + (size_t)g * T_HID);
#pragma unroll
        for (int j = 0; j < 16; j++) w[j] = p[j];
    }
    const float bias = (half == 0) ? (b_ih[g] + b_hh[g]) : 0.0f;

    // ---- phase-B / gxn identities ----
    const int su = tid >> 6;             // seq within block (= wave id), 0..7
    const int uu = tid & 63;             // hidden unit
    float cst = 0.0f;                    // cell state for (su, uu)

    // gxn: thread = (seq su, out j, k-chunk nk); weights held in 8 regs
    const int nj = (tid >> 3) & 7;
    const int nk = tid & 7;
    float wn[8];
#pragma unroll
    for (int i = 0; i < 8; i++) wn[i] = w_ih_n[nj * 64 + nk * 8 + i];
    const float nbias = b_ih_n[nj] + b_hh_n[nj];
    const int sglb = s0 + su;
    const int nb = sglb / NOTES, nn = sglb % NOTES;
    float* gout = gxn + ((size_t)nn * NBT + (size_t)nb * TLEN) * 8 + nj;

    // prefetch lane assignment (160 threads cover SB*20 float4 of one t-slice)
    const int pls = tid / 20;
    const int pj  = tid % 20;

    // ---- init: zero h, load x(t=0) ----
    hbuf[su][uu] = 0.0f;                 // 512 threads = 8*64 exactly
    if (tid < SB * 20) {
        ((float4*)xbuf[pls])[pj] =
            *(const float4*)(x + ((size_t)(s0 + pls) * TLEN) * IN_DIM + 4 * pj);
    }
    __syncthreads();

    for (int t = 0; t < TLEN; t++) {
        // ---- region A ----
        // issue x(t+1) prefetch early
        float4 xp;
        const bool pf = (t + 1 < TLEN) && (tid < SB * 20);
        if (pf) {
            xp = *(const float4*)(x + ((size_t)(s0 + pls) * TLEN + (t + 1)) * IN_DIM + 4 * pj);
        }

        // gxn for previous step's h (hbuf holds h_{t-1}; skip t==0 = zero state)
        if (t > 0) {
            float p = 0.0f;
#pragma unroll
            for (int i = 0; i < 8; i++) p = fmaf(wn[i], hbuf[su][nk * 8 + i], p);
            p += __shfl_xor(p, 1);
            p += __shfl_xor(p, 2);
            p += __shfl_xor(p, 4);
            if (nk == 0) gout[(size_t)(t - 1) * 8] = p + nbias;
        }

        // partial gate pre-activations for all 8 sequences
        float acc[SB];
#pragma unroll
        for (int s = 0; s < SB; s++) acc[s] = bias;
        if (half == 0) {
#pragma unroll
            for (int j = 0; j < 20; j++) {
                const float4 wv = w[j];
#pragma unroll
                for (int s = 0; s < SB; s++) {
                    const float4 v = ((const float4*)xbuf[s])[j];
                    acc[s] = fmaf(wv.w, v.w, fmaf(wv.z, v.z,
                             fmaf(wv.y, v.y, fmaf(wv.x, v.x, acc[s]))));
                }
            }
            float* Gp = &G0[0][0];
#pragma unroll
            for (int s = 0; s < SB; s++) Gp[s * 256 + g] = acc[s];
        } else {
#pragma unroll
            for (int j = 0; j < 16; j++) {
                const float4 wv = w[j];
#pragma unroll
                for (int s = 0; s < SB; s++) {
                    const float4 v = ((const float4*)hbuf[s])[j];
                    acc[s] = fmaf(wv.w, v.w, fmaf(wv.z, v.z,
                             fmaf(wv.y, v.y, fmaf(wv.x, v.x, acc[s]))));
                }
            }
            float* Gp = &G1[0][0];
#pragma unroll
            for (int s = 0; s < SB; s++) Gp[s * 256 + g] = acc[s];
        }
        __syncthreads();   // barrier 1: G0/G1 complete

        // ---- region B: combine partials, activate, update state ----
        {
            const float i_p = G0[su][uu]        + G1[su][uu];
            const float f_p = G0[su][64 + uu]   + G1[su][64 + uu];
            const float g_p = G0[su][128 + uu]  + G1[su][128 + uu];
            const float o_p = G0[su][192 + uu]  + G1[su][192 + uu];
            const float iv = sigf(i_p);
            const float fv = sigf(f_p);
            const float gv = tanhf(g_p);
            const float ov = sigf(o_p);
            cst = fv * cst + iv * gv;
            const float h = ov * tanhf(cst);
            hbuf[su][uu] = h;
        }
        if (pf) ((float4*)xbuf[pls])[pj] = xp;
        __syncthreads();   // barrier 2: hbuf/xbuf ready for next step
    }

    // epilogue: gxn for the final h (t = 127)
    {
        float p = 0.0f;
#pragma unroll
        for (int i = 0; i < 8; i++) p = fmaf(wn[i], hbuf[su][nk * 8 + i], p);
        p += __shfl_xor(p, 1);
        p += __shfl_xor(p, 2);
        p += __shfl_xor(p, 4);
        if (nk == 0) gout[(size_t)(TLEN - 1) * 8] = p + nbias;
    }
}

// ---------------------------------------------------------------------------
// Kernel C: note-LSTM scan over 78 notes, fresh zero state per (b,t).
// One thread per bt; gxn reads are h-independent -> software prefetch.
// ---------------------------------------------------------------------------
__global__ __launch_bounds__(64)
void note_scan_kernel(const float* __restrict__ gxn,
                      const float* __restrict__ w_hh_n,
                      float* __restrict__ out) {
    const int bt = blockIdx.x * 64 + threadIdx.x;         // < 8192
    float wh[16];
#pragma unroll
    for (int i = 0; i < 16; i++) wh[i] = w_hh_n[i];       // [8][2] row-major
    float h0 = 0.f, h1 = 0.f, c0 = 0.f, c1 = 0.f;

    const float4* gp = (const float4*)gxn;                // f4 index = (n*NBT+bt)*2
    float* op = out + (size_t)bt * (NOTES * N_HID);

    size_t idx = (size_t)bt * 2;
    float4 ga = gp[idx], gb = gp[idx + 1];
    for (int n = 0; n < NOTES; n++) {
        float4 na, nb2;
        if (n + 1 < NOTES) {
            const size_t nidx = ((size_t)(n + 1) * NBT + bt) * 2;
            na  = gp[nidx];
            nb2 = gp[nidx + 1];
        }
        const float i0 = ga.x + wh[0]  * h0 + wh[1]  * h1;
        const float i1 = ga.y + wh[2]  * h0 + wh[3]  * h1;
        const float f0 = ga.z + wh[4]  * h0 + wh[5]  * h1;
        const float f1 = ga.w + wh[6]  * h0 + wh[7]  * h1;
        const float g0 = gb.x + wh[8]  * h0 + wh[9]  * h1;
        const float g1 = gb.y + wh[10] * h0 + wh[11] * h1;
        const float o0 = gb.z + wh[12] * h0 + wh[13] * h1;
        const float o1 = gb.w + wh[14] * h0 + wh[15] * h1;
        c0 = sigf(f0) * c0 + sigf(i0) * tanhf(g0);
        c1 = sigf(f1) * c1 + sigf(i1) * tanhf(g1);
        h0 = sigf(o0) * tanhf(c0);
        h1 = sigf(o1) * tanhf(c1);
        op[n * 2 + 0] = (h0 > 0.5f) ? 1.0f : 0.0f;
        op[n * 2 + 1] = (h1 > 0.5f) ? 1.0f : 0.0f;
        ga = na; gb = nb2;
    }
}

// ---------------------------------------------------------------------------
extern "C" void kernel_launch(void* const* d_in, const int* in_sizes, int n_in,
                              void* d_out, int out_size, void* d_ws, size_t ws_size,
                              hipStream_t stream) {
    const float* x      = (const float*)d_in[0];  // (64,78,128,80)
    const float* w_ih_t = (const float*)d_in[1];  // (256,80)
    const float* w_hh_t = (const float*)d_in[2];  // (256,64)
    const float* b_ih_t = (const float*)d_in[3];  // (256)
    const float* b_hh_t = (const float*)d_in[4];  // (256)
    const float* w_ih_n = (const float*)d_in[5];  // (8,64)
    const float* w_hh_n = (const float*)d_in[6];  // (8,2)
    const float* b_ih_n = (const float*)d_in[7];  // (8)
    const float* b_hh_n = (const float*)d_in[8];  // (8)
    float* out = (float*)d_out;                   // (64,128,156)

    // workspace: gxn = [78][8192][8] fp32 = 20.4 MB
    float* gxn = (float*)d_ws;

    time_lstm_fused<<<NSEQ / SB, 512, 0, stream>>>(
        x, w_ih_t, w_hh_t, b_ih_t, b_hh_t, w_ih_n, b_ih_n, b_hh_n, gxn);
    note_scan_kernel<<<NBT / 64, 64, 0, stream>>>(gxn, w_hh_n, out);
}